// Round 6
// baseline (102.669 us; speedup 1.0000x reference)
//
#include <hip/hip_runtime.h>
#include <math.h>

#define POOL 7
#define FH 50
#define FW 50
#define FC 1024
#define FC4 (FC / 4)        // 256 vf4 per spatial cell
#define CHUNKS 4            // channel chunks; 64 vf4 (256 ch) per chunk
#define F4C 64              // vf4 per cell per chunk (one wave-wide load)
#define RS (FW * FC4)       // row stride in vf4
#define JGROUPS 4           // column-bin groups: {0,1},{2,3},{4,5},{6}
#define UNITS_PER_ROI (POOL * JGROUPS)   // 28
#define GRID 1024           // 4 blocks/CU, co-resident (persistent waves)

typedef float vf4 __attribute__((ext_vector_type(4)));

static __device__ __forceinline__ vf4 vmax4(vf4 a, vf4 b) {
    vf4 r;
    r.x = fmaxf(a.x, b.x);
    r.y = fmaxf(a.y, b.y);
    r.z = fmaxf(a.z, b.z);
    r.w = fmaxf(a.w, b.w);
    return r;
}

// Specialized inner loops for wstep = W (compile-time), valid when
// wstep >= 1: col bins j<6 have width EXACTLY W (no empty-bin adjustment,
// no clamping since ROI is inside [0,1] -> region inside the feature map).
// jg < 3: 2 rows x 2W cols of unconditional independent loads per iter,
// a0/a1 split at compile-time column W. jg == 3: last bin, runtime width
// bw in [W, W+6], fixed W+6 loads with clamped index (dup-max is free).
template<int W>
static __device__ __forceinline__ void pool_w(
    const vf4* __restrict__ base,    // fm4 + (chunk*F4C + lane)
    int r0, int nrows, int w0, int rw, int jg,
    vf4& a0, vf4& a1)
{
    if (jg < 3) {
        const int c0 = w0 + (jg * 2) * W;
        const vf4* p = base + (size_t)r0 * RS + (size_t)c0 * FC4;
        int t = 0;
        for (; t + 2 <= nrows; t += 2) {
            vf4 v0[2 * W], v1[2 * W];
#pragma unroll
            for (int k = 0; k < 2 * W; ++k) v0[k] = p[k * FC4];
#pragma unroll
            for (int k = 0; k < 2 * W; ++k) v1[k] = p[RS + k * FC4];
#pragma unroll
            for (int k = 0; k < W; ++k) a0 = vmax4(a0, vmax4(v0[k], v1[k]));
#pragma unroll
            for (int k = W; k < 2 * W; ++k) a1 = vmax4(a1, vmax4(v0[k], v1[k]));
            p += 2 * RS;
        }
        if (t < nrows) {
            vf4 v0[2 * W];
#pragma unroll
            for (int k = 0; k < 2 * W; ++k) v0[k] = p[k * FC4];
#pragma unroll
            for (int k = 0; k < W; ++k) a0 = vmax4(a0, v0[k]);
#pragma unroll
            for (int k = W; k < 2 * W; ++k) a1 = vmax4(a1, v0[k]);
        }
    } else {
        const int bw = rw - 6 * W;          // [W, W+6]
        const int c0 = w0 + 6 * W;
        const vf4* p = base + (size_t)r0 * RS + (size_t)c0 * FC4;
        for (int r = 0; r < nrows; ++r) {
            vf4 v[W + 6];
#pragma unroll
            for (int k = 0; k < W + 6; ++k) {
                const int kc = (k < bw) ? k : (bw - 1);   // clamp: dup-max ok
                v[k] = p[kc * FC4];
            }
#pragma unroll
            for (int k = 0; k < W + 6; ++k) a0 = vmax4(a0, v[k]);
            p += RS;
        }
    }
}

// PERSISTENT-WAVE RoI max-pool.
//
// Rounds 0/2/5 — radically different per-wave structures (1-acc chained,
// 2-acc, 4-12 branch-free loads in flight) — all land at ~46 us (<0.2%
// spread). Per-wave MLP, L2 channels (R4), and setup cost (R1) are all
// refuted as limiters. The only measured occupancy (R1) was 15.8% = ~5
// waves/CU: short-lived blocks (~2 us) mean time-averaged residency stays
// tiny through ramp/drain/straggler decay, and 5 waves x ~2 chained loads
// / ~600cy L2 latency = the measured 15 B/cy/CU. Limiter theory: resident-
// wave starvation, not per-wave structure.
//
// This version: 1024 blocks = exactly 4/CU, guaranteed co-resident by
// __launch_bounds__(256,4) (16 waves/CU, VGPR<=128). Each wave grid-strides
// over ~8 units (stride 1024 within its chunk): waves live the whole
// kernel — zero dispatch churn, no generational ramp, work variance
// averaged over 8 units kills the tail. Unit decomposition, chunk-pinning
// (chunk=b&3, XCD b%8 round-robin, 2.56MB slab L2-resident, FETCH 8.3MB
// confirmed) and the R5 specialized bodies are unchanged.
__global__ __launch_bounds__(256, 4) void roipool_kernel(
    const float* __restrict__ fm,     // [FH, FW, FC]
    const float* __restrict__ rois,   // [N, 4] (y1, x1, y2, x2) normalized
    float* __restrict__ out,          // [N, 7, 7, FC]
    int nunits)                       // N * POOL * JGROUPS units per chunk
{
    const int b     = blockIdx.x;
    const int chunk = b & (CHUNKS - 1);       // pinned per XCD
    const int wave  = threadIdx.x >> 6;
    const int lane  = threadIdx.x & 63;
    const int wv    = (b >> 2) * 4 + wave;    // 0..GRID-1 within this chunk

    const int f4 = chunk * F4C + lane;        // [0, 256)
    const vf4* base = reinterpret_cast<const vf4*>(fm) + f4;

    for (int u = wv; u < nunits; u += GRID) {
        const int n   = u / UNITS_PER_ROI;    // const divisor -> magic mul
        const int rem = u - n * UNITS_PER_ROI;
        const int i   = rem >> 2;
        const int jg  = rem & 3;
        const int j0  = jg * 2;
        const int jcnt = (jg < JGROUPS - 1) ? 2 : 1;

        // ROI corners: truncating float->int cast, matching jnp astype(int32)
        const float4 roi = reinterpret_cast<const float4*>(rois)[n];
        const int h0 = (int)((float)FH * roi.x);
        const int w0 = (int)((float)FW * roi.y);
        const int h1 = (int)((float)FH * roi.z);
        const int w1 = (int)((float)FW * roi.w);
        const int rh = h1 - h0;
        const int rw = w1 - w0;
        const int hstep = rh / POOL;
        const int wstep = rw / POOL;

        vf4 a0 = {-INFINITY, -INFINITY, -INFINITY, -INFINITY};
        vf4 a1 = a0;

        if (hstep >= 1 && wstep >= 1 && wstep <= 3) {
            // ---- specialized fast paths (always taken for this dist) ----
            const int r0    = h0 + i * hstep;
            const int nrows = (i < POOL - 1) ? hstep : (rh - 6 * hstep);
            switch (wstep) {
                case 1: pool_w<1>(base, r0, nrows, w0, rw, jg, a0, a1); break;
                case 2: pool_w<2>(base, r0, nrows, w0, rw, jg, a0, a1); break;
                default: pool_w<3>(base, r0, nrows, w0, rw, jg, a0, a1); break;
            }
        } else {
            // ---- generic fallback (degenerate ROIs): round-2 code ----
            int sh = i * hstep;
            int eh = (i < POOL - 1) ? (i + 1) * hstep : rh;
            if (sh == eh) { if (eh < rh) eh += 1; else sh -= 1; }
            const int rr0 = max(0, h0 + sh);
            const int rr1 = min(FH, h0 + eh);

            int c0[2], c1[2];
#pragma unroll
            for (int t = 0; t < 2; ++t) {
                const int j = j0 + t;
                if (j < POOL) {
                    int sw = j * wstep;
                    int ew = (j < POOL - 1) ? (j + 1) * wstep : rw;
                    if (sw == ew) { if (ew < rw) ew += 1; else sw -= 1; }
                    c0[t] = max(0, w0 + sw);
                    c1[t] = min(FW, w0 + ew);
                } else {
                    c0[t] = 0; c1[t] = 0;
                }
            }
            for (int r = rr0; r < rr1; ++r) {
                const vf4* rowp = base + (size_t)r * RS;
#pragma unroll
                for (int t = 0; t < 2; ++t) {
                    vf4 acc = (t == 0) ? a0 : a1;
                    for (int c = c0[t]; c < c1[t]; ++c) {
                        acc = vmax4(acc, rowp[c * FC4]);
                    }
                    if (t == 0) a0 = acc; else a1 = acc;
                }
            }
        }

        vf4* o = reinterpret_cast<vf4*>(out)
               + (size_t)(n * 49 + i * 7 + j0) * FC4 + f4;
        __builtin_nontemporal_store(a0, o);
        if (jcnt == 2) {
            __builtin_nontemporal_store(a1, o + (size_t)FC4);
        }
    }
}

extern "C" void kernel_launch(void* const* d_in, const int* in_sizes, int n_in,
                              void* d_out, int out_size, void* d_ws, size_t ws_size,
                              hipStream_t stream) {
    const float* features = (const float*)d_in[0];  // [1,50,50,1024]
    const float* rois     = (const float*)d_in[1];  // [N,4]
    float* out            = (float*)d_out;          // [N,7,7,1024]
    const int N = in_sizes[1] / 4;

    const int nunits = N * UNITS_PER_ROI;           // 8400 units per chunk
    // persistent grid: 1024 blocks (4/CU), chunk = b&3 pinned per XCD,
    // each wave strides units by GRID within its chunk
    dim3 grid(GRID);
    dim3 block(256);
    roipool_kernel<<<grid, block, 0, stream>>>(features, rois, out, nunits);
}

// Round 7
// 101.549 us; speedup vs baseline: 1.0110x; 1.0110x over previous
//
#include <hip/hip_runtime.h>
#include <math.h>

#define POOL 7
#define FH 50
#define FW 50
#define FC 1024
#define FC4 (FC / 4)        // 256 vf4 per spatial cell
#define CHUNKS 4            // channel chunks; 64 vf4 (256 ch) per chunk
#define F4C 64              // vf4 per cell per chunk (one wave-wide load)
#define RS (FW * FC4)       // row stride in vf4
#define JGROUPS 4
#define UNITS_PER_ROI (POOL * JGROUPS)   // 28
#define GRID 1024           // persistent: 4 blocks/CU
#define NCELLS (FH * FW)    // 2500
#define TBL_ELEMS ((size_t)NCELLS * FC)  // floats per table
#define TBL_BYTES (TBL_ELEMS * sizeof(float))   // 10,240,000 B

typedef float vf4 __attribute__((ext_vector_type(4)));

static __device__ __forceinline__ vf4 vmax4(vf4 a, vf4 b) {
    vf4 r;
    r.x = fmaxf(a.x, b.x);
    r.y = fmaxf(a.y, b.y);
    r.z = fmaxf(a.z, b.z);
    r.w = fmaxf(a.w, b.w);
    return r;
}

// Build shifted-max tables over fm (same [2500][1024] layout as fm):
//   P1[r][c] = max(fm[r][c], fm[r+1][c])   (row pair,  mask bit 0)
//   C1[r][c] = max(fm[r][c], fm[r][c+1])   (col pair,  mask bit 1)
//   Q [r][c] = 2x2 max                     (bit 2)
// Edge entries (r=49 / c=49) are clamped duplicates and never consumed
// (lookups always lie fully inside a bin <= the feature map).
// One block per cell: 256 threads = 256 vf4 = the cell's 1024 floats.
__global__ __launch_bounds__(256) void build_tables(
    const float* __restrict__ fm,
    float* __restrict__ p1, float* __restrict__ c1, float* __restrict__ q,
    int mask)
{
    const int cell = blockIdx.x;
    const int t    = threadIdx.x;
    const int r    = cell / FW;
    const int c    = cell - r * FW;
    const int rr   = (r + 1 < FH) ? r + 1 : r;
    const int cc   = (c + 1 < FW) ? c + 1 : c;

    const vf4* fm4 = reinterpret_cast<const vf4*>(fm);
    const size_t i00 = (size_t)cell * FC4 + t;
    const vf4 v00 = fm4[(size_t)(r  * FW + c ) * FC4 + t];
    const vf4 v10 = fm4[(size_t)(rr * FW + c ) * FC4 + t];
    const vf4 v01 = fm4[(size_t)(r  * FW + cc) * FC4 + t];
    const vf4 v11 = fm4[(size_t)(rr * FW + cc) * FC4 + t];

    if (mask & 1) reinterpret_cast<vf4*>(p1)[i00] = vmax4(v00, v10);
    if (mask & 2) reinterpret_cast<vf4*>(c1)[i00] = vmax4(v00, v01);
    if (mask & 4) reinterpret_cast<vf4*>(q)[i00]  = vmax4(vmax4(v00, v10), vmax4(v01, v11));
}

// Persistent-wave RoI max-pool, table-accelerated.
//
// Six rounds of structural variation (per-wave MLP 2->12, occupancy 5->16
// waves/CU, 1KB vs 4KB strides, persistent vs churned blocks) all land at
// 44-46 us with ~433 MB read at a fixed ~16 B/cy/CU = 1 line / 4 cy / CU —
// the L1-miss service rate (our pattern is ~100% L1-miss by construction:
// bins within a block partition columns; cross-ROI overlap lands on other
// CUs). The only unvaried lever is READ VOLUME. A bin of hr x wc cells is
// computed from ceil(hr/2) x ceil(wc/2) lookups of the 2x2-max table Q
// (overlapping placement is idempotent under max), C1 for hr==1 rows, P1
// for wc==1 cols => ~3x fewer loads (~150 MB).
//
// Unchanged invariants: chunk = b&3 pinned per XCD (b%8 round-robin; the
// 2.56 MB/chunk slices stay L2/LLC-resident — FETCH 8.4 MB confirmed),
// fast path only when hstep>=1 && wstep>=1 (exact-partition semantics
// verified in R5), generic fallback otherwise, persistent GRID=1024.
__global__ __launch_bounds__(256, 4) void roipool_kernel(
    const float* __restrict__ fm,     // [FH, FW, FC]
    const float* __restrict__ rois,   // [N, 4] (y1, x1, y2, x2) normalized
    float* __restrict__ out,          // [N, 7, 7, FC]
    int nunits,
    const float* __restrict__ p1, const float* __restrict__ c1,
    const float* __restrict__ q, int mask)
{
    const int b     = blockIdx.x;
    const int chunk = b & (CHUNKS - 1);       // pinned per XCD
    const int wave  = threadIdx.x >> 6;
    const int lane  = threadIdx.x & 63;
    const int wv    = (b >> 2) * 4 + wave;

    const int f4 = chunk * F4C + lane;        // [0, 256)

    for (int u = wv; u < nunits; u += GRID) {
        const int n   = u / UNITS_PER_ROI;
        const int rem = u - n * UNITS_PER_ROI;
        const int i   = rem >> 2;
        const int jg  = rem & 3;
        const int j0  = jg * 2;
        const int jcnt = (jg < JGROUPS - 1) ? 2 : 1;

        // ROI corners: truncating float->int cast, matching jnp astype(int32)
        const float4 roi = reinterpret_cast<const float4*>(rois)[n];
        const int h0 = (int)((float)FH * roi.x);
        const int w0 = (int)((float)FW * roi.y);
        const int h1 = (int)((float)FH * roi.z);
        const int w1 = (int)((float)FW * roi.w);
        const int rh = h1 - h0;
        const int rw = w1 - w0;
        const int hstep = rh / POOL;
        const int wstep = rw / POOL;

        vf4* o = reinterpret_cast<vf4*>(out)
               + (size_t)(n * 49 + i * 7 + j0) * FC4 + f4;

        if (hstep >= 1 && wstep >= 1) {
            // ---- table-accelerated fast path (bins exactly partition) ----
            const int row0 = h0 + i * hstep;
            const int hr   = (i < POOL - 1) ? hstep : (rh - 6 * hstep); // >=1
            for (int t = 0; t < jcnt; ++t) {
                const int j    = j0 + t;
                const int wc   = (j < POOL - 1) ? wstep : (rw - 6 * wstep);
                const int col0 = w0 + j * wstep;

                // pick table: span (sr, sc), lookup counts rn, cn
                const float* tb; int sr, sc;
                if (hr >= 2 && wc >= 2 && (mask & 4))      { tb = q;  sr = 2; sc = 2; }
                else if (hr == 1 && wc >= 2 && (mask & 2)) { tb = c1; sr = 1; sc = 2; }
                else if (wc == 1 && hr >= 2 && (mask & 1)) { tb = p1; sr = 2; sc = 1; }
                else                                       { tb = fm; sr = 1; sc = 1; }
                const int rn = (sr == 2) ? ((hr + 1) >> 1) : hr;
                const int cn = (sc == 2) ? ((wc + 1) >> 1) : wc;

                const vf4* tb4 = reinterpret_cast<const vf4*>(tb) + f4;
                vf4 acc = {-INFINITY, -INFINITY, -INFINITY, -INFINITY};
                for (int a = 0; a < rn; ++a) {
                    // span-2 positions 0,2,..., last clamped to hr-2 (overlap ok)
                    const int ro = (sr == 2) ? min(2 * a, hr - 2) : a;
                    const vf4* rowp = tb4 + (size_t)(row0 + ro) * RS;
                    int bb = 0;
                    for (; bb + 2 <= cn; bb += 2) {
                        const int co0 = (sc == 2) ? min(2 * bb, wc - 2) : bb;
                        const int co1 = (sc == 2) ? min(2 * (bb + 1), wc - 2) : (bb + 1);
                        vf4 x = rowp[(size_t)(col0 + co0) * FC4];
                        vf4 y = rowp[(size_t)(col0 + co1) * FC4];
                        acc = vmax4(acc, vmax4(x, y));
                    }
                    if (bb < cn) {
                        const int co = (sc == 2) ? min(2 * bb, wc - 2) : bb;
                        acc = vmax4(acc, rowp[(size_t)(col0 + co) * FC4]);
                    }
                }
                __builtin_nontemporal_store(acc, o + (size_t)t * FC4);
            }
        } else {
            // ---- generic fallback (degenerate ROIs): round-2 code ----
            int sh = i * hstep;
            int eh = (i < POOL - 1) ? (i + 1) * hstep : rh;
            if (sh == eh) { if (eh < rh) eh += 1; else sh -= 1; }
            const int rr0 = max(0, h0 + sh);
            const int rr1 = min(FH, h0 + eh);

            int c0[2], c1b[2];
#pragma unroll
            for (int t = 0; t < 2; ++t) {
                const int j = j0 + t;
                if (j < POOL) {
                    int sw = j * wstep;
                    int ew = (j < POOL - 1) ? (j + 1) * wstep : rw;
                    if (sw == ew) { if (ew < rw) ew += 1; else sw -= 1; }
                    c0[t]  = max(0, w0 + sw);
                    c1b[t] = min(FW, w0 + ew);
                } else {
                    c0[t] = 0; c1b[t] = 0;
                }
            }
            vf4 a0 = {-INFINITY, -INFINITY, -INFINITY, -INFINITY};
            vf4 a1 = a0;
            const vf4* base = reinterpret_cast<const vf4*>(fm) + f4;
            for (int r = rr0; r < rr1; ++r) {
                const vf4* rowp = base + (size_t)r * RS;
#pragma unroll
                for (int t = 0; t < 2; ++t) {
                    vf4 acc = (t == 0) ? a0 : a1;
                    for (int c = c0[t]; c < c1b[t]; ++c) {
                        acc = vmax4(acc, rowp[c * FC4]);
                    }
                    if (t == 0) a0 = acc; else a1 = acc;
                }
            }
            __builtin_nontemporal_store(a0, o);
            if (jcnt == 2) {
                __builtin_nontemporal_store(a1, o + (size_t)FC4);
            }
        }
    }
}

extern "C" void kernel_launch(void* const* d_in, const int* in_sizes, int n_in,
                              void* d_out, int out_size, void* d_ws, size_t ws_size,
                              hipStream_t stream) {
    const float* features = (const float*)d_in[0];  // [1,50,50,1024]
    const float* rois     = (const float*)d_in[1];  // [N,4]
    float* out            = (float*)d_out;          // [N,7,7,1024]
    const int N = in_sizes[1] / 4;
    const int nunits = N * UNITS_PER_ROI;

    // tiered workspace: 3 tables (30.72 MB) > Q-only (10.24 MB) > none
    int mask = 0;
    float *p1 = nullptr, *c1 = nullptr, *q = nullptr;
    float* ws = (float*)d_ws;
    if (ws_size >= 3 * TBL_BYTES) {
        p1 = ws; c1 = ws + TBL_ELEMS; q = ws + 2 * TBL_ELEMS; mask = 7;
    } else if (ws_size >= TBL_BYTES) {
        q = ws; mask = 4;
    }

    dim3 block(256);
    if (mask) {
        build_tables<<<dim3(NCELLS), block, 0, stream>>>(features, p1, c1, q, mask);
    }
    roipool_kernel<<<dim3(GRID), block, 0, stream>>>(features, rois, out, nunits,
                                                     p1, c1, q, mask);
}